// Round 6
// baseline (144.937 us; speedup 1.0000x reference)
//
#include <hip/hip_runtime.h>

#define T_SEQ 2048
#define C_DIM 1024
#define H_DIM 64
#define B_DIM 8
#define NROW (B_DIM * T_SEQ)  // 16384

typedef __attribute__((ext_vector_type(8))) short short8;
typedef __attribute__((ext_vector_type(4))) float f32x4;

__device__ __forceinline__ short f2bf(float f) {
  unsigned u = __builtin_bit_cast(unsigned, f);
  u += 0x7fffu + ((u >> 16) & 1u);  // round-to-nearest-even
  return (short)(u >> 16);
}

// ---------------------------------------------------------------------------
// P: Wt2 in FRAGMENT-LINEAR order (unchanged).
// ---------------------------------------------------------------------------
__global__ __launch_bounds__(256) void w_prep(
    const float* __restrict__ Wq, const float* __restrict__ Wk,
    const float* __restrict__ Wv, short* __restrict__ Wt2) {
  const int unit = blockIdx.x * 256 + threadIdx.x;  // 0..24575
  const int lane = unit & 63;
  const int t = unit >> 6;
  const int kh = t & 3;
  const int g = t >> 2;    // kc*12 + ntg
  const int ntg = g % 12;
  const int kc = g / 12;
  const int n16 = lane & 15, quad = lane >> 4;
  const int mat = ntg >> 2;
  const int h = (ntg & 3) * 16 + n16;
  const int kb = kc * 128 + kh * 32 + quad * 8;
  const float* W = (mat == 0) ? Wq : (mat == 1 ? Wk : Wv);
  short8 v;
#pragma unroll
  for (int e = 0; e < 8; ++e) v[e] = f2bf(W[(size_t)(kb + e) * H_DIM + h]);
  *(short8*)(Wt2 + (size_t)unit * 8) = v;
}

// LDS address (in shorts) for A frag unit (tile, kh, quad, n16); XOR-swizzled.
__device__ __forceinline__ int lds_addr(int tile, int kh, int qd, int nn) {
  return tile * 2048 + kh * 512 + (qd * 16 + (nn ^ ((kh * 4 + qd) & 7))) * 8;
}

// ---------------------------------------------------------------------------
// K1: QKV projection, BM=16.  1024 blocks (4/CU, ~110 VGPR -> deeper wave
// co-residency) x 256 thr, BN=192, BK=128, 8 chunks.  vs BM=32: 4 independent
// blocks per CU overlap each other's barrier/lgkm drains and double the
// outstanding HBM-load depth (qkv was at 52% of achievable read BW).  Cost:
// B L2-traffic doubles (each block reads full 384 KB Wt2) -- ~4 TB/s/XCD,
// under the L2 ceiling and overlapped with HBM.  Per-output accumulation
// order unchanged -> bit-identical results.
// ---------------------------------------------------------------------------
__global__ __launch_bounds__(256) void qkv_gemm(
    const float* __restrict__ x, const short* __restrict__ Wt2,
    short* __restrict__ q, short* __restrict__ k, short* __restrict__ vt) {
  __shared__ __align__(16) short As[2][2048];  // 2 x 4 KB (16 x 128 bf16)
  const int tid = threadIdx.x;
  const int w = tid >> 6, lane = tid & 63;
  const int n16 = lane & 15, quad = lane >> 4;
  const int row0 = blockIdx.x * 16;

  f32x4 acc[3];
#pragma unroll
  for (int ln = 0; ln < 3; ++ln) acc[ln] = (f32x4){0.f, 0.f, 0.f, 0.f};

  // A staging: thread covers one 8-float group of the 16x128 tile.
  const int sr = tid >> 4, f = tid & 15;
  const float* ap = x + (size_t)(row0 + sr) * C_DIM + f * 8;
  const int soff = lds_addr(0, f >> 2, f & 3, sr & 15);

  int swz[4];
#pragma unroll
  for (int kh = 0; kh < 4; ++kh)
    swz[kh] = (quad * 16 + (n16 ^ ((kh * 4 + quad) & 7))) * 8;

  const short* bbase = Wt2 + (size_t)(w * 3) * 2048 + (size_t)lane * 8;

  float4 astg[2][2];  // [chunk parity][2 x float4]
  short8 bfr[12];

#define STAGE_A(d, p)                                    \
  {                                                      \
    short8 av;                                           \
    _Pragma("unroll") for (int e = 0; e < 4; ++e) {      \
      av[e] = f2bf(((const float*)&astg[d][0])[e]);      \
      av[e + 4] = f2bf(((const float*)&astg[d][1])[e]);  \
    }                                                    \
    *(short8*)(&As[p][0] + soff) = av;                   \
  }

  // prologue: issue A(0), A(1), B(0); stage A(0)
  astg[0][0] = *(const float4*)(ap);
  astg[0][1] = *(const float4*)(ap + 4);
  astg[1][0] = *(const float4*)(ap + 128);
  astg[1][1] = *(const float4*)(ap + 132);
#pragma unroll
  for (int ln = 0; ln < 3; ++ln)
#pragma unroll
    for (int kh = 0; kh < 4; ++kh)
      bfr[ln * 4 + kh] = *(const short8*)(bbase + ln * 2048 + kh * 512);
  STAGE_A(0, 0);
  asm volatile("s_waitcnt lgkmcnt(0)" ::: "memory");
  __builtin_amdgcn_sched_barrier(0);
  __builtin_amdgcn_s_barrier();
  __builtin_amdgcn_sched_barrier(0);

#pragma unroll
  for (int kc = 0; kc < 8; ++kc) {
    const short* asb = &As[kc & 1][0];
#pragma unroll
    for (int kh = 0; kh < 4; ++kh) {
      const short8 a0 = *(const short8*)(asb + kh * 512 + swz[kh]);
#pragma unroll
      for (int ln = 0; ln < 3; ++ln)
        acc[ln] = __builtin_amdgcn_mfma_f32_16x16x32_bf16(
            a0, bfr[ln * 4 + kh], acc[ln], 0, 0, 0);
    }
    if (kc < 7) {
      const short* bc = bbase + (size_t)(kc + 1) * 24576;
#pragma unroll
      for (int ln = 0; ln < 3; ++ln)
#pragma unroll
        for (int kh = 0; kh < 4; ++kh)
          bfr[ln * 4 + kh] = *(const short8*)(bc + ln * 2048 + kh * 512);
      if (kc < 6) {
        astg[kc & 1][0] = *(const float4*)(ap + (kc + 2) * 128);
        astg[kc & 1][1] = *(const float4*)(ap + (kc + 2) * 128 + 4);
      }
      STAGE_A((kc + 1) & 1, (kc + 1) & 1);
      asm volatile("s_waitcnt lgkmcnt(0)" ::: "memory");
      __builtin_amdgcn_sched_barrier(0);
      __builtin_amdgcn_s_barrier();
      __builtin_amdgcn_sched_barrier(0);
    }
  }
#undef STAGE_A

  const int b = row0 >> 11;
#pragma unroll
  for (int ln = 0; ln < 3; ++ln) {
    const int ntg = w * 3 + ln;
    const int mat = ntg >> 2;
    const int cl = (ntg & 3) * 16 + n16;
#pragma unroll
    for (int r = 0; r < 4; ++r) {
      const int row = row0 + quad * 4 + r;
      const float v = acc[ln][r];
      if (mat == 0)
        q[(size_t)row * H_DIM + cl] = f2bf(v * 0.125f);
      else if (mat == 1)
        k[(size_t)row * H_DIM + cl] = f2bf(v);
      else
        vt[((size_t)b * H_DIM + cl) * T_SEQ + (row & (T_SEQ - 1))] = f2bf(v);
    }
  }
}

// ---------------------------------------------------------------------------
// K2: paired-tile flash attention -- EXACT R2 kernel (best measured: 137.0
// total).  R3/R4/R5 inner-loop and occupancy variants all regressed or were
// neutral; reverted verbatim.
// ---------------------------------------------------------------------------
__global__ __launch_bounds__(256) void attn_mfma(
    const short* __restrict__ q, const short* __restrict__ k,
    const short* __restrict__ vt, float* __restrict__ out) {
  __shared__ __align__(16) short pbuf[4][2048];    // per-wave: A | B
  __shared__ __align__(16) float oshare[3][2048];  // A | B
  __shared__ __align__(16) float lshare[3][512];   // A | B
  const int tid = threadIdx.x;
  const int w = tid >> 6;
  const int lane = tid & 63;
  const int n16 = lane & 15, quad = lane >> 4;
  const int b = blockIdx.x & 7;       // b == XCD slot -> K/V L2-resident
  const int pa = blockIdx.x >> 3;     // 0..63
  const int r0a = pa * 16;            // low tile rows
  const int r0b = (127 - pa) * 16;    // high tile rows

  const short* kb = k + (size_t)b * T_SEQ * H_DIM;
  const short* vb = vt + (size_t)b * H_DIM * T_SEQ;
  const short* qpa = q + ((size_t)b * T_SEQ + r0a) * H_DIM;
  const short* qpb = q + ((size_t)b * T_SEQ + r0b) * H_DIM;

  short8 aqA[2], aqB[2];
  aqA[0] = *(const short8*)(qpa + (size_t)n16 * H_DIM + quad * 8);
  aqA[1] = *(const short8*)(qpa + (size_t)n16 * H_DIM + 32 + quad * 8);
  aqB[0] = *(const short8*)(qpb + (size_t)n16 * H_DIM + quad * 8);
  aqB[1] = *(const short8*)(qpb + (size_t)n16 * H_DIM + 32 + quad * 8);

  f32x4 OA[4], OB[4];
#pragma unroll
  for (int i = 0; i < 4; ++i) {
    OA[i] = (f32x4){0.f, 0.f, 0.f, 0.f};
    OB[i] = (f32x4){0.f, 0.f, 0.f, 0.f};
  }
  float lsA[4] = {0.f, 0.f, 0.f, 0.f};
  float lsB[4] = {0.f, 0.f, 0.f, 0.f};

  const int nj = (r0b + 16 + 63) >> 6;   // j-tiles of 64 for the high tile
  const int njA = (r0a + 16 + 63) >> 6;  // j-tiles needed by the low tile

  for (int jt = w; jt < nj; jt += 4) {
    const int j0 = jt * 64;
    const bool actA = (jt < njA);  // wave-uniform

    short8 bk[4][2];
#pragma unroll
    for (int nt = 0; nt < 4; ++nt) {
      const short* kp = kb + (size_t)(j0 + nt * 16 + n16) * H_DIM + quad * 8;
      bk[nt][0] = *(const short8*)kp;
      bk[nt][1] = *(const short8*)(kp + 32);
    }

    // --- scores: high tile always, low tile while in range ---
    f32x4 sB[4];
#pragma unroll
    for (int nt = 0; nt < 4; ++nt) {
      f32x4 z = (f32x4){0.f, 0.f, 0.f, 0.f};
      z = __builtin_amdgcn_mfma_f32_16x16x32_bf16(aqB[0], bk[nt][0], z, 0, 0, 0);
      z = __builtin_amdgcn_mfma_f32_16x16x32_bf16(aqB[1], bk[nt][1], z, 0, 0, 0);
      sB[nt] = z;
    }
    f32x4 sA[4];
    if (actA) {
#pragma unroll
      for (int nt = 0; nt < 4; ++nt) {
        f32x4 z = (f32x4){0.f, 0.f, 0.f, 0.f};
        z = __builtin_amdgcn_mfma_f32_16x16x32_bf16(aqA[0], bk[nt][0], z, 0, 0, 0);
        z = __builtin_amdgcn_mfma_f32_16x16x32_bf16(aqA[1], bk[nt][1], z, 0, 0, 0);
        sA[nt] = z;
      }
    }

    // --- exp + causal mask + pack to LDS ---
    const bool fullB = (j0 + 64 <= r0b);
#pragma unroll
    for (int nt = 0; nt < 4; ++nt) {
      const int base =
          (nt >> 1) * 512 + ((((nt & 1) << 1) | (n16 >> 3)) * 128) + (n16 & 7);
#pragma unroll
      for (int r = 0; r < 4; ++r) {
        float p;
        if (fullB) {
          p = __expf(sB[nt][r]);
        } else {
          const int j = j0 + nt * 16 + n16;
          const int row = r0b + quad * 4 + r;
          p = (j <= row) ? __expf(sB[nt][r]) : 0.f;
        }
        lsB[r] += p;
        pbuf[w][1024 + base + (quad * 4 + r) * 8] = f2bf(p);
      }
    }
    if (actA) {
      const bool fullA = (j0 + 64 <= r0a);
#pragma unroll
      for (int nt = 0; nt < 4; ++nt) {
        const int base =
            (nt >> 1) * 512 + ((((nt & 1) << 1) | (n16 >> 3)) * 128) + (n16 & 7);
#pragma unroll
        for (int r = 0; r < 4; ++r) {
          float p;
          if (fullA) {
            p = __expf(sA[nt][r]);
          } else {
            const int j = j0 + nt * 16 + n16;
            const int row = r0a + quad * 4 + r;
            p = (j <= row) ? __expf(sA[nt][r]) : 0.f;
          }
          lsA[r] += p;
          pbuf[w][base + (quad * 4 + r) * 8] = f2bf(p);
        }
      }
    }

    // --- V fragments (shared by both tiles) ---
    short8 bv[4][2];
#pragma unroll
    for (int ht = 0; ht < 4; ++ht)
#pragma unroll
      for (int kh = 0; kh < 2; ++kh)
        bv[ht][kh] = *(const short8*)(vb + (size_t)(ht * 16 + n16) * T_SEQ +
                                      j0 + kh * 32 + quad * 8);

    // --- PV ---
    const short8 apB0 = *(const short8*)(&pbuf[w][1024] + lane * 8);
    const short8 apB1 = *(const short8*)(&pbuf[w][1536] + lane * 8);
#pragma unroll
    for (int ht = 0; ht < 4; ++ht) {
      OB[ht] = __builtin_amdgcn_mfma_f32_16x16x32_bf16(apB0, bv[ht][0], OB[ht], 0, 0, 0);
      OB[ht] = __builtin_amdgcn_mfma_f32_16x16x32_bf16(apB1, bv[ht][1], OB[ht], 0, 0, 0);
    }
    if (actA) {
      const short8 apA0 = *(const short8*)(&pbuf[w][0] + lane * 8);
      const short8 apA1 = *(const short8*)(&pbuf[w][512] + lane * 8);
#pragma unroll
      for (int ht = 0; ht < 4; ++ht) {
        OA[ht] = __builtin_amdgcn_mfma_f32_16x16x32_bf16(apA0, bv[ht][0], OA[ht], 0, 0, 0);
        OA[ht] = __builtin_amdgcn_mfma_f32_16x16x32_bf16(apA1, bv[ht][1], OA[ht], 0, 0, 0);
      }
    }
  }

  // --- cross-wave reduction ---
  if (w != 0) {
#pragma unroll
    for (int ht = 0; ht < 4; ++ht)
#pragma unroll
      for (int r = 0; r < 4; ++r) {
        oshare[w - 1][(ht * 4 + r) * 64 + lane] = OA[ht][r];
        oshare[w - 1][1024 + (ht * 4 + r) * 64 + lane] = OB[ht][r];
      }
#pragma unroll
    for (int r = 0; r < 4; ++r) {
      lshare[w - 1][r * 64 + lane] = lsA[r];
      lshare[w - 1][256 + r * 64 + lane] = lsB[r];
    }
  }
  __syncthreads();
  if (w == 0) {
#pragma unroll
    for (int ht = 0; ht < 4; ++ht)
#pragma unroll
      for (int r = 0; r < 4; ++r) {
        float a = OA[ht][r], bb = OB[ht][r];
#pragma unroll
        for (int ow = 0; ow < 3; ++ow) {
          a += oshare[ow][(ht * 4 + r) * 64 + lane];
          bb += oshare[ow][1024 + (ht * 4 + r) * 64 + lane];
        }
        OA[ht][r] = a;
        OB[ht][r] = bb;
      }
#pragma unroll
    for (int r = 0; r < 4; ++r) {
      float va = lsA[r], vb2 = lsB[r];
#pragma unroll
      for (int ow = 0; ow < 3; ++ow) {
        va += lshare[ow][r * 64 + lane];
        vb2 += lshare[ow][256 + r * 64 + lane];
      }
      va += __shfl_xor(va, 1);
      va += __shfl_xor(va, 2);
      va += __shfl_xor(va, 4);
      va += __shfl_xor(va, 8);
      vb2 += __shfl_xor(vb2, 1);
      vb2 += __shfl_xor(vb2, 2);
      vb2 += __shfl_xor(vb2, 4);
      vb2 += __shfl_xor(vb2, 8);
      lsA[r] = va;
      lsB[r] = vb2;
    }
#pragma unroll
    for (int ht = 0; ht < 4; ++ht)
#pragma unroll
      for (int r = 0; r < 4; ++r) {
        out[((size_t)b * T_SEQ + r0a + quad * 4 + r) * H_DIM + ht * 16 + n16] =
            OA[ht][r] / lsA[r];
        out[((size_t)b * T_SEQ + r0b + quad * 4 + r) * H_DIM + ht * 16 + n16] =
            OB[ht][r] / lsB[r];
      }
  }
}

extern "C" void kernel_launch(void* const* d_in, const int* in_sizes, int n_in,
                              void* d_out, int out_size, void* d_ws,
                              size_t ws_size, hipStream_t stream) {
  const float* x = (const float*)d_in[0];
  const float* Wq = (const float*)d_in[1];
  const float* Wk = (const float*)d_in[2];
  const float* Wv = (const float*)d_in[3];

  char* ws = (char*)d_ws;
  short* Wt = (short*)ws;                       // 384 KB (fragment-linear)
  short* q = (short*)(ws + 3 * 64 * 1024 * 2);  // 2 MB each
  short* kk = (short*)(ws + 3 * 64 * 1024 * 2 + 2097152);
  short* vt = (short*)(ws + 3 * 64 * 1024 * 2 + 2 * 2097152);

  w_prep<<<96, 256, 0, stream>>>(Wq, Wk, Wv, Wt);
  qkv_gemm<<<NROW / 16, 256, 0, stream>>>(x, Wt, q, kk, vt);
  attn_mfma<<<B_DIM * (T_SEQ / 32), 256, 0, stream>>>(q, kk, vt, (float*)d_out);
}

// Round 8
// 137.384 us; speedup vs baseline: 1.0550x; 1.0550x over previous
//
#include <hip/hip_runtime.h>

#define T_SEQ 2048
#define C_DIM 1024
#define H_DIM 64
#define B_DIM 8
#define NROW (B_DIM * T_SEQ)  // 16384

typedef __attribute__((ext_vector_type(8))) short short8;
typedef __attribute__((ext_vector_type(4))) float f32x4;
typedef __attribute__((ext_vector_type(4))) int i32x4;

__device__ __forceinline__ short f2bf(float f) {
  unsigned u = __builtin_bit_cast(unsigned, f);
  u += 0x7fffu + ((u >> 16) & 1u);  // round-to-nearest-even
  return (short)(u >> 16);
}

// pack two f32 -> one u32 of 2 bf16 (RNE, same bits as f2bf pair)
__device__ __forceinline__ unsigned pk_bf16(float lo, float hi) {
  unsigned r;
  asm("v_cvt_pk_bf16_f32 %0, %1, %2" : "=v"(r) : "v"(lo), "v"(hi));
  return r;
}

// ---------------------------------------------------------------------------
// P: Wt2 in FRAGMENT-LINEAR order (unchanged).
// ---------------------------------------------------------------------------
__global__ __launch_bounds__(256) void w_prep(
    const float* __restrict__ Wq, const float* __restrict__ Wk,
    const float* __restrict__ Wv, short* __restrict__ Wt2) {
  const int unit = blockIdx.x * 256 + threadIdx.x;  // 0..24575
  const int lane = unit & 63;
  const int t = unit >> 6;
  const int kh = t & 3;
  const int g = t >> 2;    // kc*12 + ntg
  const int ntg = g % 12;
  const int kc = g / 12;
  const int n16 = lane & 15, quad = lane >> 4;
  const int mat = ntg >> 2;
  const int h = (ntg & 3) * 16 + n16;
  const int kb = kc * 128 + kh * 32 + quad * 8;
  const float* W = (mat == 0) ? Wq : (mat == 1 ? Wk : Wv);
  short8 v;
#pragma unroll
  for (int e = 0; e < 8; ++e) v[e] = f2bf(W[(size_t)(kb + e) * H_DIM + h]);
  *(short8*)(Wt2 + (size_t)unit * 8) = v;
}

// LDS address (in shorts) for A frag unit (tile, kh, quad, n16); XOR-swizzled.
__device__ __forceinline__ int lds_addr(int tile, int kh, int qd, int nn) {
  return tile * 2048 + kh * 512 + (qd * 16 + (nn ^ ((kh * 4 + qd) & 7))) * 8;
}

// ---------------------------------------------------------------------------
// K1: QKV projection -- exact R2 version (BM=32, grid 512).
// ---------------------------------------------------------------------------
__global__ __launch_bounds__(256, 2) void qkv_gemm(
    const float* __restrict__ x, const short* __restrict__ Wt2,
    short* __restrict__ q, short* __restrict__ k, short* __restrict__ vt) {
  __shared__ __align__(16) short As[2][4096];  // 2 x 8 KB (32 x 128 bf16)
  const int tid = threadIdx.x;
  const int w = tid >> 6, lane = tid & 63;
  const int n16 = lane & 15, quad = lane >> 4;
  const int row0 = blockIdx.x * 32;

  f32x4 acc[2][3];
#pragma unroll
  for (int mt = 0; mt < 2; ++mt)
#pragma unroll
    for (int ln = 0; ln < 3; ++ln) acc[mt][ln] = (f32x4){0.f, 0.f, 0.f, 0.f};

  const int u20 = tid, u21 = 256 + tid;
  const int sr0 = u20 >> 4, f0 = u20 & 15;
  const int sr1 = u21 >> 4, f1 = u21 & 15;
  const float* ap0 = x + (size_t)(row0 + sr0) * C_DIM + f0 * 8;
  const float* ap1 = x + (size_t)(row0 + sr1) * C_DIM + f1 * 8;
  const int soff0 = lds_addr(sr0 >> 4, f0 >> 2, f0 & 3, sr0 & 15);
  const int soff1 = lds_addr(sr1 >> 4, f1 >> 2, f1 & 3, sr1 & 15);

  int swz[4];
#pragma unroll
  for (int kh = 0; kh < 4; ++kh)
    swz[kh] = (quad * 16 + (n16 ^ ((kh * 4 + quad) & 7))) * 8;

  const short* bbase = Wt2 + (size_t)(w * 3) * 2048 + (size_t)lane * 8;

  float4 astg[2][4];
  short8 bfr[12];

#define STAGE_A(d, p)                                      \
  {                                                        \
    short8 av0, av1;                                       \
    _Pragma("unroll") for (int e = 0; e < 4; ++e) {        \
      av0[e] = f2bf(((const float*)&astg[d][0])[e]);       \
      av0[e + 4] = f2bf(((const float*)&astg[d][1])[e]);   \
      av1[e] = f2bf(((const float*)&astg[d][2])[e]);       \
      av1[e + 4] = f2bf(((const float*)&astg[d][3])[e]);   \
    }                                                      \
    *(short8*)(&As[p][0] + soff0) = av0;                   \
    *(short8*)(&As[p][0] + soff1) = av1;                   \
  }

  astg[0][0] = *(const float4*)(ap0);
  astg[0][1] = *(const float4*)(ap0 + 4);
  astg[0][2] = *(const float4*)(ap1);
  astg[0][3] = *(const float4*)(ap1 + 4);
  astg[1][0] = *(const float4*)(ap0 + 128);
  astg[1][1] = *(const float4*)(ap0 + 132);
  astg[1][2] = *(const float4*)(ap1 + 128);
  astg[1][3] = *(const float4*)(ap1 + 132);
#pragma unroll
  for (int ln = 0; ln < 3; ++ln)
#pragma unroll
    for (int kh = 0; kh < 4; ++kh)
      bfr[ln * 4 + kh] = *(const short8*)(bbase + ln * 2048 + kh * 512);
  STAGE_A(0, 0);
  asm volatile("s_waitcnt lgkmcnt(0)" ::: "memory");
  __builtin_amdgcn_sched_barrier(0);
  __builtin_amdgcn_s_barrier();
  __builtin_amdgcn_sched_barrier(0);

#pragma unroll
  for (int kc = 0; kc < 8; ++kc) {
    const short* asb = &As[kc & 1][0];
#pragma unroll
    for (int kh = 0; kh < 4; ++kh) {
      const short8 a0 = *(const short8*)(asb + kh * 512 + swz[kh]);
      const short8 a1 = *(const short8*)(asb + 2048 + kh * 512 + swz[kh]);
#pragma unroll
      for (int ln = 0; ln < 3; ++ln) {
        acc[0][ln] = __builtin_amdgcn_mfma_f32_16x16x32_bf16(
            a0, bfr[ln * 4 + kh], acc[0][ln], 0, 0, 0);
        acc[1][ln] = __builtin_amdgcn_mfma_f32_16x16x32_bf16(
            a1, bfr[ln * 4 + kh], acc[1][ln], 0, 0, 0);
      }
    }
    if (kc < 7) {
      const short* bc = bbase + (size_t)(kc + 1) * 24576;
#pragma unroll
      for (int ln = 0; ln < 3; ++ln)
#pragma unroll
        for (int kh = 0; kh < 4; ++kh)
          bfr[ln * 4 + kh] = *(const short8*)(bc + ln * 2048 + kh * 512);
      if (kc < 6) {
        astg[kc & 1][0] = *(const float4*)(ap0 + (kc + 2) * 128);
        astg[kc & 1][1] = *(const float4*)(ap0 + (kc + 2) * 128 + 4);
        astg[kc & 1][2] = *(const float4*)(ap1 + (kc + 2) * 128);
        astg[kc & 1][3] = *(const float4*)(ap1 + (kc + 2) * 128 + 4);
      }
      STAGE_A((kc + 1) & 1, (kc + 1) & 1);
      asm volatile("s_waitcnt lgkmcnt(0)" ::: "memory");
      __builtin_amdgcn_sched_barrier(0);
      __builtin_amdgcn_s_barrier();
      __builtin_amdgcn_sched_barrier(0);
    }
  }
#undef STAGE_A

  const int b = row0 >> 11;
#pragma unroll
  for (int mt = 0; mt < 2; ++mt)
#pragma unroll
    for (int ln = 0; ln < 3; ++ln) {
      const int ntg = w * 3 + ln;
      const int mat = ntg >> 2;
      const int cl = (ntg & 3) * 16 + n16;
#pragma unroll
      for (int r = 0; r < 4; ++r) {
        const int row = row0 + mt * 16 + quad * 4 + r;
        const float v = acc[mt][ln][r];
        if (mat == 0)
          q[(size_t)row * H_DIM + cl] = f2bf(v * 0.125f);
        else if (mat == 1)
          k[(size_t)row * H_DIM + cl] = f2bf(v);
        else
          vt[((size_t)b * H_DIM + cl) * T_SEQ + (row & (T_SEQ - 1))] = f2bf(v);
      }
    }
}

// ---------------------------------------------------------------------------
// K2: paired-tile flash attention with IN-REGISTER softmax (T12-style).
// vs R2: the P pack/unpack LDS round-trip (64 ds_write_b16 + lgkm drain +
// 8 ds_read_b128 per iter -- squarely on the serial chain between QK and PV)
// is replaced by a register-only path:
//   * QK^T computed SWAPPED: z = mfma(bk, aq) = S^T.  Same fragment bytes,
//     but each lane now holds P[row=n16][j = nt*16 + quad*4 + r].
//   * v_cvt_pk_bf16_f32 packs r-pairs (RNE == f2bf, bit-identical P).
//   * PV A-frag needs P[row=n16][j = 32h + quad*8 + e]: dest word (h,i) at
//     quad qd comes from source lane qs = 2(qd&1)+(i>>1), source word
//     [nt = 2h+(qd>>1)][i&1].  Routed with 3 shfl_xor (masks 16/32/48):
//     x16 carries (q>=2)?whi:wlo; x32/x48 carry (q<2)?whi:wlo; assembly:
//     q0:{local,x16} q1:{x48,x32} q2:{x32,x48} q3:{x16,local}.  (Full
//     enumeration of all (qd,i) verified against the fragment layouts.)
// O is bit-identical to R2 (same P bits, same MFMA order); lsum totals are
// equal with a different summation order (ulp-level drift only).  The scalar
// per-row lsum is remapped to R2's (quad,r) convention (partials at n16<4)
// so the entire verified R2 cross-wave epilogue runs unchanged.
// ---------------------------------------------------------------------------
__global__ __launch_bounds__(256) void attn_mfma(
    const short* __restrict__ q, const short* __restrict__ k,
    const short* __restrict__ vt, float* __restrict__ out) {
  __shared__ __align__(16) float oshare[3][2048];  // A | B
  __shared__ __align__(16) float lshare[3][512];   // A | B
  const int tid = threadIdx.x;
  const int w = tid >> 6;
  const int lane = tid & 63;
  const int n16 = lane & 15, quad = lane >> 4;
  const int b = blockIdx.x & 7;     // b == XCD slot -> K/V L2-resident
  const int pa = blockIdx.x >> 3;   // 0..63
  const int r0a = pa * 16;          // low tile rows
  const int r0b = (127 - pa) * 16;  // high tile rows

  const short* kb = k + (size_t)b * T_SEQ * H_DIM;
  const short* vb = vt + (size_t)b * H_DIM * T_SEQ;
  const short* qpa = q + ((size_t)b * T_SEQ + r0a) * H_DIM;
  const short* qpb = q + ((size_t)b * T_SEQ + r0b) * H_DIM;

  short8 aqA[2], aqB[2];
  aqA[0] = *(const short8*)(qpa + (size_t)n16 * H_DIM + quad * 8);
  aqA[1] = *(const short8*)(qpa + (size_t)n16 * H_DIM + 32 + quad * 8);
  aqB[0] = *(const short8*)(qpb + (size_t)n16 * H_DIM + quad * 8);
  aqB[1] = *(const short8*)(qpb + (size_t)n16 * H_DIM + 32 + quad * 8);

  f32x4 OA[4], OB[4];
#pragma unroll
  for (int i = 0; i < 4; ++i) {
    OA[i] = (f32x4){0.f, 0.f, 0.f, 0.f};
    OB[i] = (f32x4){0.f, 0.f, 0.f, 0.f};
  }
  float lsAsc = 0.f, lsBsc = 0.f;  // per-lane partial for row = n16

  const int nj = (r0b + 16 + 63) >> 6;   // j-tiles of 64 for the high tile
  const int njA = (r0a + 16 + 63) >> 6;  // j-tiles needed by the low tile

  for (int jt = w; jt < nj; jt += 4) {
    const int j0 = jt * 64;
    const bool actA = (jt < njA);  // wave-uniform

    short8 bk[4][2];
#pragma unroll
    for (int nt = 0; nt < 4; ++nt) {
      const short* kp = kb + (size_t)(j0 + nt * 16 + n16) * H_DIM + quad * 8;
      bk[nt][0] = *(const short8*)kp;
      bk[nt][1] = *(const short8*)(kp + 32);
    }

    // --- scores, SWAPPED: sX[nt][r] = S[row=n16][j = j0+nt*16+quad*4+r] ---
    f32x4 sB[4];
#pragma unroll
    for (int nt = 0; nt < 4; ++nt) {
      f32x4 z = (f32x4){0.f, 0.f, 0.f, 0.f};
      z = __builtin_amdgcn_mfma_f32_16x16x32_bf16(bk[nt][0], aqB[0], z, 0, 0, 0);
      z = __builtin_amdgcn_mfma_f32_16x16x32_bf16(bk[nt][1], aqB[1], z, 0, 0, 0);
      sB[nt] = z;
    }
    f32x4 sA[4];
    if (actA) {
#pragma unroll
      for (int nt = 0; nt < 4; ++nt) {
        f32x4 z = (f32x4){0.f, 0.f, 0.f, 0.f};
        z = __builtin_amdgcn_mfma_f32_16x16x32_bf16(bk[nt][0], aqA[0], z, 0, 0, 0);
        z = __builtin_amdgcn_mfma_f32_16x16x32_bf16(bk[nt][1], aqA[1], z, 0, 0, 0);
        sA[nt] = z;
      }
    }

    // --- exp + causal mask + register pack (no LDS) ---
    unsigned wB[4][2], wA[4][2];
    const bool fullB = (j0 + 64 <= r0b);
#pragma unroll
    for (int nt = 0; nt < 4; ++nt) {
      float p[4];
#pragma unroll
      for (int r = 0; r < 4; ++r) {
        if (fullB) {
          p[r] = __expf(sB[nt][r]);
        } else {
          const int j = j0 + nt * 16 + quad * 4 + r;
          p[r] = (j <= r0b + n16) ? __expf(sB[nt][r]) : 0.f;
        }
        lsBsc += p[r];
      }
      wB[nt][0] = pk_bf16(p[0], p[1]);
      wB[nt][1] = pk_bf16(p[2], p[3]);
    }
    if (actA) {
      const bool fullA = (j0 + 64 <= r0a);
#pragma unroll
      for (int nt = 0; nt < 4; ++nt) {
        float p[4];
#pragma unroll
        for (int r = 0; r < 4; ++r) {
          if (fullA) {
            p[r] = __expf(sA[nt][r]);
          } else {
            const int j = j0 + nt * 16 + quad * 4 + r;
            p[r] = (j <= r0a + n16) ? __expf(sA[nt][r]) : 0.f;
          }
          lsAsc += p[r];
        }
        wA[nt][0] = pk_bf16(p[0], p[1]);
        wA[nt][1] = pk_bf16(p[2], p[3]);
      }
    }

    // --- V fragments (same placement as R2) ---
    short8 bv[4][2];
#pragma unroll
    for (int ht = 0; ht < 4; ++ht)
#pragma unroll
      for (int kh = 0; kh < 2; ++kh)
        bv[ht][kh] = *(const short8*)(vb + (size_t)(ht * 16 + n16) * T_SEQ +
                                      j0 + kh * 32 + quad * 8);

    // --- in-register exchange -> PV A-fragments, then PV ---
#define EXCHANGE(WSRC, AP0, AP1)                                          \
  {                                                                       \
    i32x4 apw[2];                                                         \
    _Pragma("unroll") for (int h = 0; h < 2; ++h) {                       \
      _Pragma("unroll") for (int ww = 0; ww < 2; ++ww) {                  \
        const unsigned wlo = WSRC[2 * h][ww];                             \
        const unsigned whi = WSRC[2 * h + 1][ww];                         \
        const unsigned pay16 = (quad >= 2) ? whi : wlo;                   \
        const unsigned pay2 = (quad < 2) ? whi : wlo;                     \
        const unsigned x16 = (unsigned)__shfl_xor((int)pay16, 16);        \
        const unsigned x32 = (unsigned)__shfl_xor((int)pay2, 32);         \
        const unsigned x48 = (unsigned)__shfl_xor((int)pay2, 48);         \
        const unsigned lo =                                               \
            quad == 0 ? wlo : quad == 1 ? x48 : quad == 2 ? x32 : x16;    \
        const unsigned hi =                                               \
            quad == 0 ? x16 : quad == 1 ? x32 : quad == 2 ? x48 : whi;    \
        apw[h][ww] = (int)lo;                                             \
        apw[h][2 + ww] = (int)hi;                                         \
      }                                                                   \
    }                                                                     \
    AP0 = __builtin_bit_cast(short8, apw[0]);                             \
    AP1 = __builtin_bit_cast(short8, apw[1]);                             \
  }

    short8 apB0, apB1;
    EXCHANGE(wB, apB0, apB1);
#pragma unroll
    for (int ht = 0; ht < 4; ++ht) {
      OB[ht] = __builtin_amdgcn_mfma_f32_16x16x32_bf16(apB0, bv[ht][0], OB[ht], 0, 0, 0);
      OB[ht] = __builtin_amdgcn_mfma_f32_16x16x32_bf16(apB1, bv[ht][1], OB[ht], 0, 0, 0);
    }
    if (actA) {
      short8 apA0, apA1;
      EXCHANGE(wA, apA0, apA1);
#pragma unroll
      for (int ht = 0; ht < 4; ++ht) {
        OA[ht] = __builtin_amdgcn_mfma_f32_16x16x32_bf16(apA0, bv[ht][0], OA[ht], 0, 0, 0);
        OA[ht] = __builtin_amdgcn_mfma_f32_16x16x32_bf16(apA1, bv[ht][1], OA[ht], 0, 0, 0);
      }
    }
#undef EXCHANGE
  }

  // remap scalar row-partials (row = n16) to R2's (quad,r) convention:
  // row (quad*4+r)'s four quad-partials land at n16 = 0..3; zeros elsewhere.
  // The unchanged epilogue's xor(1,2,4,8) reduction then sums them exactly.
  float lsA[4], lsB[4];
#pragma unroll
  for (int r = 0; r < 4; ++r) {
    const int src = (n16 & 3) * 16 + quad * 4 + r;
    const float vA = __shfl(lsAsc, src);
    const float vB = __shfl(lsBsc, src);
    lsA[r] = (n16 < 4) ? vA : 0.f;
    lsB[r] = (n16 < 4) ? vB : 0.f;
  }

  // --- cross-wave reduction (byte-identical to R2) ---
  if (w != 0) {
#pragma unroll
    for (int ht = 0; ht < 4; ++ht)
#pragma unroll
      for (int r = 0; r < 4; ++r) {
        oshare[w - 1][(ht * 4 + r) * 64 + lane] = OA[ht][r];
        oshare[w - 1][1024 + (ht * 4 + r) * 64 + lane] = OB[ht][r];
      }
#pragma unroll
    for (int r = 0; r < 4; ++r) {
      lshare[w - 1][r * 64 + lane] = lsA[r];
      lshare[w - 1][256 + r * 64 + lane] = lsB[r];
    }
  }
  __syncthreads();
  if (w == 0) {
#pragma unroll
    for (int ht = 0; ht < 4; ++ht)
#pragma unroll
      for (int r = 0; r < 4; ++r) {
        float a = OA[ht][r], bb = OB[ht][r];
#pragma unroll
        for (int ow = 0; ow < 3; ++ow) {
          a += oshare[ow][(ht * 4 + r) * 64 + lane];
          bb += oshare[ow][1024 + (ht * 4 + r) * 64 + lane];
        }
        OA[ht][r] = a;
        OB[ht][r] = bb;
      }
#pragma unroll
    for (int r = 0; r < 4; ++r) {
      float va = lsA[r], vb2 = lsB[r];
#pragma unroll
      for (int ow = 0; ow < 3; ++ow) {
        va += lshare[ow][r * 64 + lane];
        vb2 += lshare[ow][256 + r * 64 + lane];
      }
      va += __shfl_xor(va, 1);
      va += __shfl_xor(va, 2);
      va += __shfl_xor(va, 4);
      va += __shfl_xor(va, 8);
      vb2 += __shfl_xor(vb2, 1);
      vb2 += __shfl_xor(vb2, 2);
      vb2 += __shfl_xor(vb2, 4);
      vb2 += __shfl_xor(vb2, 8);
      lsA[r] = va;
      lsB[r] = vb2;
    }
#pragma unroll
    for (int ht = 0; ht < 4; ++ht)
#pragma unroll
      for (int r = 0; r < 4; ++r) {
        out[((size_t)b * T_SEQ + r0a + quad * 4 + r) * H_DIM + ht * 16 + n16] =
            OA[ht][r] / lsA[r];
        out[((size_t)b * T_SEQ + r0b + quad * 4 + r) * H_DIM + ht * 16 + n16] =
            OB[ht][r] / lsB[r];
      }
  }
}

extern "C" void kernel_launch(void* const* d_in, const int* in_sizes, int n_in,
                              void* d_out, int out_size, void* d_ws,
                              size_t ws_size, hipStream_t stream) {
  const float* x = (const float*)d_in[0];
  const float* Wq = (const float*)d_in[1];
  const float* Wk = (const float*)d_in[2];
  const float* Wv = (const float*)d_in[3];

  char* ws = (char*)d_ws;
  short* Wt = (short*)ws;                       // 384 KB (fragment-linear)
  short* q = (short*)(ws + 3 * 64 * 1024 * 2);  // 2 MB each
  short* kk = (short*)(ws + 3 * 64 * 1024 * 2 + 2097152);
  short* vt = (short*)(ws + 3 * 64 * 1024 * 2 + 2 * 2097152);

  w_prep<<<96, 256, 0, stream>>>(Wq, Wk, Wv, Wt);
  qkv_gemm<<<NROW / 32, 256, 0, stream>>>(x, Wt, q, kk, vt);
  attn_mfma<<<B_DIM * (T_SEQ / 32), 256, 0, stream>>>(q, kk, vt, (float*)d_out);
}

// Round 9
// 133.801 us; speedup vs baseline: 1.0832x; 1.0268x over previous
//
#include <hip/hip_runtime.h>

#define T_SEQ 2048
#define C_DIM 1024
#define H_DIM 64
#define B_DIM 8
#define NROW (B_DIM * T_SEQ)  // 16384

typedef __attribute__((ext_vector_type(8))) short short8;
typedef __attribute__((ext_vector_type(4))) float f32x4;
typedef __attribute__((ext_vector_type(4))) int i32x4;

__device__ __forceinline__ short f2bf(float f) {
  unsigned u = __builtin_bit_cast(unsigned, f);
  u += 0x7fffu + ((u >> 16) & 1u);  // round-to-nearest-even
  return (short)(u >> 16);
}

// pack two f32 -> one u32 of 2 bf16 (RNE, same bits as f2bf pair)
__device__ __forceinline__ unsigned pk_bf16(float lo, float hi) {
  unsigned r;
  asm("v_cvt_pk_bf16_f32 %0, %1, %2" : "=v"(r) : "v"(lo), "v"(hi));
  return r;
}

// ---------------------------------------------------------------------------
// P: Wt2 in FRAGMENT-LINEAR order (unchanged).
// ---------------------------------------------------------------------------
__global__ __launch_bounds__(256) void w_prep(
    const float* __restrict__ Wq, const float* __restrict__ Wk,
    const float* __restrict__ Wv, short* __restrict__ Wt2) {
  const int unit = blockIdx.x * 256 + threadIdx.x;  // 0..24575
  const int lane = unit & 63;
  const int t = unit >> 6;
  const int kh = t & 3;
  const int g = t >> 2;    // kc*12 + ntg
  const int ntg = g % 12;
  const int kc = g / 12;
  const int n16 = lane & 15, quad = lane >> 4;
  const int mat = ntg >> 2;
  const int h = (ntg & 3) * 16 + n16;
  const int kb = kc * 128 + kh * 32 + quad * 8;
  const float* W = (mat == 0) ? Wq : (mat == 1 ? Wk : Wv);
  short8 v;
#pragma unroll
  for (int e = 0; e < 8; ++e) v[e] = f2bf(W[(size_t)(kb + e) * H_DIM + h]);
  *(short8*)(Wt2 + (size_t)unit * 8) = v;
}

// LDS address (in shorts) for A frag unit (tile, kh, quad, n16); XOR-swizzled.
__device__ __forceinline__ int lds_addr(int tile, int kh, int qd, int nn) {
  return tile * 2048 + kh * 512 + (qd * 16 + (nn ^ ((kh * 4 + qd) & 7))) * 8;
}

// ---------------------------------------------------------------------------
// K1: QKV projection -- exact R2 version (BM=32, grid 512).
// ---------------------------------------------------------------------------
__global__ __launch_bounds__(256, 2) void qkv_gemm(
    const float* __restrict__ x, const short* __restrict__ Wt2,
    short* __restrict__ q, short* __restrict__ k, short* __restrict__ vt) {
  __shared__ __align__(16) short As[2][4096];  // 2 x 8 KB (32 x 128 bf16)
  const int tid = threadIdx.x;
  const int w = tid >> 6, lane = tid & 63;
  const int n16 = lane & 15, quad = lane >> 4;
  const int row0 = blockIdx.x * 32;

  f32x4 acc[2][3];
#pragma unroll
  for (int mt = 0; mt < 2; ++mt)
#pragma unroll
    for (int ln = 0; ln < 3; ++ln) acc[mt][ln] = (f32x4){0.f, 0.f, 0.f, 0.f};

  const int u20 = tid, u21 = 256 + tid;
  const int sr0 = u20 >> 4, f0 = u20 & 15;
  const int sr1 = u21 >> 4, f1 = u21 & 15;
  const float* ap0 = x + (size_t)(row0 + sr0) * C_DIM + f0 * 8;
  const float* ap1 = x + (size_t)(row0 + sr1) * C_DIM + f1 * 8;
  const int soff0 = lds_addr(sr0 >> 4, f0 >> 2, f0 & 3, sr0 & 15);
  const int soff1 = lds_addr(sr1 >> 4, f1 >> 2, f1 & 3, sr1 & 15);

  int swz[4];
#pragma unroll
  for (int kh = 0; kh < 4; ++kh)
    swz[kh] = (quad * 16 + (n16 ^ ((kh * 4 + quad) & 7))) * 8;

  const short* bbase = Wt2 + (size_t)(w * 3) * 2048 + (size_t)lane * 8;

  float4 astg[2][4];
  short8 bfr[12];

#define STAGE_A(d, p)                                      \
  {                                                        \
    short8 av0, av1;                                       \
    _Pragma("unroll") for (int e = 0; e < 4; ++e) {        \
      av0[e] = f2bf(((const float*)&astg[d][0])[e]);       \
      av0[e + 4] = f2bf(((const float*)&astg[d][1])[e]);   \
      av1[e] = f2bf(((const float*)&astg[d][2])[e]);       \
      av1[e + 4] = f2bf(((const float*)&astg[d][3])[e]);   \
    }                                                      \
    *(short8*)(&As[p][0] + soff0) = av0;                   \
    *(short8*)(&As[p][0] + soff1) = av1;                   \
  }

  astg[0][0] = *(const float4*)(ap0);
  astg[0][1] = *(const float4*)(ap0 + 4);
  astg[0][2] = *(const float4*)(ap1);
  astg[0][3] = *(const float4*)(ap1 + 4);
  astg[1][0] = *(const float4*)(ap0 + 128);
  astg[1][1] = *(const float4*)(ap0 + 132);
  astg[1][2] = *(const float4*)(ap1 + 128);
  astg[1][3] = *(const float4*)(ap1 + 132);
#pragma unroll
  for (int ln = 0; ln < 3; ++ln)
#pragma unroll
    for (int kh = 0; kh < 4; ++kh)
      bfr[ln * 4 + kh] = *(const short8*)(bbase + ln * 2048 + kh * 512);
  STAGE_A(0, 0);
  asm volatile("s_waitcnt lgkmcnt(0)" ::: "memory");
  __builtin_amdgcn_sched_barrier(0);
  __builtin_amdgcn_s_barrier();
  __builtin_amdgcn_sched_barrier(0);

#pragma unroll
  for (int kc = 0; kc < 8; ++kc) {
    const short* asb = &As[kc & 1][0];
#pragma unroll
    for (int kh = 0; kh < 4; ++kh) {
      const short8 a0 = *(const short8*)(asb + kh * 512 + swz[kh]);
      const short8 a1 = *(const short8*)(asb + 2048 + kh * 512 + swz[kh]);
#pragma unroll
      for (int ln = 0; ln < 3; ++ln) {
        acc[0][ln] = __builtin_amdgcn_mfma_f32_16x16x32_bf16(
            a0, bfr[ln * 4 + kh], acc[0][ln], 0, 0, 0);
        acc[1][ln] = __builtin_amdgcn_mfma_f32_16x16x32_bf16(
            a1, bfr[ln * 4 + kh], acc[1][ln], 0, 0, 0);
      }
    }
    if (kc < 7) {
      const short* bc = bbase + (size_t)(kc + 1) * 24576;
#pragma unroll
      for (int ln = 0; ln < 3; ++ln)
#pragma unroll
        for (int kh = 0; kh < 4; ++kh)
          bfr[ln * 4 + kh] = *(const short8*)(bc + ln * 2048 + kh * 512);
      if (kc < 6) {
        astg[kc & 1][0] = *(const float4*)(ap0 + (kc + 2) * 128);
        astg[kc & 1][1] = *(const float4*)(ap0 + (kc + 2) * 128 + 4);
        astg[kc & 1][2] = *(const float4*)(ap1 + (kc + 2) * 128);
        astg[kc & 1][3] = *(const float4*)(ap1 + (kc + 2) * 128 + 4);
      }
      STAGE_A((kc + 1) & 1, (kc + 1) & 1);
      asm volatile("s_waitcnt lgkmcnt(0)" ::: "memory");
      __builtin_amdgcn_sched_barrier(0);
      __builtin_amdgcn_s_barrier();
      __builtin_amdgcn_sched_barrier(0);
    }
  }
#undef STAGE_A

  const int b = row0 >> 11;
#pragma unroll
  for (int mt = 0; mt < 2; ++mt)
#pragma unroll
    for (int ln = 0; ln < 3; ++ln) {
      const int ntg = w * 3 + ln;
      const int mat = ntg >> 2;
      const int cl = (ntg & 3) * 16 + n16;
#pragma unroll
      for (int r = 0; r < 4; ++r) {
        const int row = row0 + mt * 16 + quad * 4 + r;
        const float v = acc[mt][ln][r];
        if (mat == 0)
          q[(size_t)row * H_DIM + cl] = f2bf(v * 0.125f);
        else if (mat == 1)
          k[(size_t)row * H_DIM + cl] = f2bf(v);
        else
          vt[((size_t)b * H_DIM + cl) * T_SEQ + (row & (T_SEQ - 1))] = f2bf(v);
      }
    }
}

// ---------------------------------------------------------------------------
// K2: QUARTET-tile flash attention + in-register softmax (R8 inner loop).
// Block owns 4 complementary q-tiles {g, 63-g, 64+g, 127-g} (combined causal
// extent 16*254+64 = 4128 keys for every g -> perfectly uniform).  K/V is
// loaded ONCE per j-tile and consumed by up to 4 tiles: j-iter (load-event)
// count per CU drops 50 -> ~30, which the fitted two-term model
// (time = 608cy*tile-iters + 733cy*j-iters per CU; fits R1/R2/R4 within
// noise) says is the only lever that has ever moved this kernel.  Grid
// 8*32 = 256 = exactly 1 block/CU, no tail.  Per-row j-order and the
// cross-wave epilogue order are identical to R2/R8 (same jt%4==w rule within
// each tile's range) -> absmax bit-identical.  LDS 60 KB; peak VGPR ~200-230
// (bk dead before bv loads; no launch_bounds cap so no forced spills).
// ---------------------------------------------------------------------------
__global__ __launch_bounds__(256) void attn_mfma(
    const short* __restrict__ q, const short* __restrict__ k,
    const short* __restrict__ vt, float* __restrict__ out) {
  __shared__ __align__(16) float oshare[3][4096];  // 4 tiles x 1024
  __shared__ __align__(16) float lshare[3][1024];  // 4 tiles x 256
  const int tid = threadIdx.x;
  const int w = tid >> 6;
  const int lane = tid & 63;
  const int n16 = lane & 15, quad = lane >> 4;
  const int b = blockIdx.x & 7;   // b == XCD slot -> K/V L2-resident
  const int g = blockIdx.x >> 3;  // 0..31

  int r0t[4], nj[4];
  r0t[0] = g * 16;
  r0t[1] = (63 - g) * 16;
  r0t[2] = (64 + g) * 16;
  r0t[3] = (127 - g) * 16;
#pragma unroll
  for (int t = 0; t < 4; ++t) nj[t] = (r0t[t] + 79) >> 6;

  const short* kb = k + (size_t)b * T_SEQ * H_DIM;
  const short* vb = vt + (size_t)b * H_DIM * T_SEQ;

  short8 aq[4][2];
#pragma unroll
  for (int t = 0; t < 4; ++t) {
    const short* qp = q + ((size_t)b * T_SEQ + r0t[t] + n16) * H_DIM;
    aq[t][0] = *(const short8*)(qp + quad * 8);
    aq[t][1] = *(const short8*)(qp + 32 + quad * 8);
  }

  f32x4 O[4][4];
#pragma unroll
  for (int t = 0; t < 4; ++t)
#pragma unroll
    for (int i = 0; i < 4; ++i) O[t][i] = (f32x4){0.f, 0.f, 0.f, 0.f};
  float lssc[4] = {0.f, 0.f, 0.f, 0.f};  // per-lane partial for row = n16

  for (int jt = w; jt < nj[3]; jt += 4) {
    const int j0 = jt * 64;

    short8 bk[4][2];
#pragma unroll
    for (int nt = 0; nt < 4; ++nt) {
      const short* kp = kb + (size_t)(j0 + nt * 16 + n16) * H_DIM + quad * 8;
      bk[nt][0] = *(const short8*)kp;
      bk[nt][1] = *(const short8*)(kp + 32);
    }

    // --- per tile: swapped QK, exp+mask, register pack ---
    unsigned wp[4][4][2];
#pragma unroll
    for (int t = 0; t < 4; ++t) {
      if (jt < nj[t]) {  // wave-uniform
        f32x4 s[4];
#pragma unroll
        for (int nt = 0; nt < 4; ++nt) {
          f32x4 z = (f32x4){0.f, 0.f, 0.f, 0.f};
          z = __builtin_amdgcn_mfma_f32_16x16x32_bf16(bk[nt][0], aq[t][0], z, 0, 0, 0);
          z = __builtin_amdgcn_mfma_f32_16x16x32_bf16(bk[nt][1], aq[t][1], z, 0, 0, 0);
          s[nt] = z;
        }
        const bool full = (j0 + 64 <= r0t[t]);
#pragma unroll
        for (int nt = 0; nt < 4; ++nt) {
          float p[4];
#pragma unroll
          for (int r = 0; r < 4; ++r) {
            if (full) {
              p[r] = __expf(s[nt][r]);
            } else {
              const int j = j0 + nt * 16 + quad * 4 + r;
              p[r] = (j <= r0t[t] + n16) ? __expf(s[nt][r]) : 0.f;
            }
            lssc[t] += p[r];
          }
          wp[t][nt][0] = pk_bf16(p[0], p[1]);
          wp[t][nt][1] = pk_bf16(p[2], p[3]);
        }
      }
    }

    // --- V fragments (shared by all active tiles) ---
    short8 bv[4][2];
#pragma unroll
    for (int ht = 0; ht < 4; ++ht)
#pragma unroll
      for (int kh = 0; kh < 2; ++kh)
        bv[ht][kh] = *(const short8*)(vb + (size_t)(ht * 16 + n16) * T_SEQ +
                                      j0 + kh * 32 + quad * 8);

    // --- in-register exchange -> PV A-fragments, then PV (per tile) ---
#define EXCHANGE(WSRC, AP0, AP1)                                          \
  {                                                                       \
    i32x4 apw[2];                                                         \
    _Pragma("unroll") for (int h = 0; h < 2; ++h) {                       \
      _Pragma("unroll") for (int ww = 0; ww < 2; ++ww) {                  \
        const unsigned wlo = WSRC[2 * h][ww];                             \
        const unsigned whi = WSRC[2 * h + 1][ww];                         \
        const unsigned pay16 = (quad >= 2) ? whi : wlo;                   \
        const unsigned pay2 = (quad < 2) ? whi : wlo;                     \
        const unsigned x16 = (unsigned)__shfl_xor((int)pay16, 16);        \
        const unsigned x32 = (unsigned)__shfl_xor((int)pay2, 32);         \
        const unsigned x48 = (unsigned)__shfl_xor((int)pay2, 48);        \
        const unsigned lo =                                               \
            quad == 0 ? wlo : quad == 1 ? x48 : quad == 2 ? x32 : x16;    \
        const unsigned hi =                                               \
            quad == 0 ? x16 : quad == 1 ? x32 : quad == 2 ? x48 : whi;    \
        apw[h][ww] = (int)lo;                                             \
        apw[h][2 + ww] = (int)hi;                                         \
      }                                                                   \
    }                                                                     \
    AP0 = __builtin_bit_cast(short8, apw[0]);                             \
    AP1 = __builtin_bit_cast(short8, apw[1]);                             \
  }

#pragma unroll
    for (int t = 0; t < 4; ++t) {
      if (jt < nj[t]) {  // wave-uniform
        short8 ap0, ap1;
        EXCHANGE(wp[t], ap0, ap1);
#pragma unroll
        for (int ht = 0; ht < 4; ++ht) {
          O[t][ht] = __builtin_amdgcn_mfma_f32_16x16x32_bf16(ap0, bv[ht][0], O[t][ht], 0, 0, 0);
          O[t][ht] = __builtin_amdgcn_mfma_f32_16x16x32_bf16(ap1, bv[ht][1], O[t][ht], 0, 0, 0);
        }
      }
    }
#undef EXCHANGE
  }

  // remap scalar row-partials (row = n16) to the (quad,r) convention:
  // row (quad*4+r)'s four quad-partials land at n16 = 0..3; zeros elsewhere.
  // The unchanged epilogue's xor(1,2,4,8) reduction then sums them exactly.
  float ls[4][4];
#pragma unroll
  for (int t = 0; t < 4; ++t)
#pragma unroll
    for (int r = 0; r < 4; ++r) {
      const int src = (n16 & 3) * 16 + quad * 4 + r;
      const float v = __shfl(lssc[t], src);
      ls[t][r] = (n16 < 4) ? v : 0.f;
    }

  // --- cross-wave reduction (R2 pattern, 4 tiles) ---
  if (w != 0) {
#pragma unroll
    for (int t = 0; t < 4; ++t) {
#pragma unroll
      for (int ht = 0; ht < 4; ++ht)
#pragma unroll
        for (int r = 0; r < 4; ++r)
          oshare[w - 1][t * 1024 + (ht * 4 + r) * 64 + lane] = O[t][ht][r];
#pragma unroll
      for (int r = 0; r < 4; ++r)
        lshare[w - 1][t * 256 + r * 64 + lane] = ls[t][r];
    }
  }
  __syncthreads();
  if (w == 0) {
#pragma unroll
    for (int t = 0; t < 4; ++t) {
#pragma unroll
      for (int ht = 0; ht < 4; ++ht)
#pragma unroll
        for (int r = 0; r < 4; ++r) {
          float a = O[t][ht][r];
#pragma unroll
          for (int ow = 0; ow < 3; ++ow)
            a += oshare[ow][t * 1024 + (ht * 4 + r) * 64 + lane];
          O[t][ht][r] = a;
        }
#pragma unroll
      for (int r = 0; r < 4; ++r) {
        float va = ls[t][r];
#pragma unroll
        for (int ow = 0; ow < 3; ++ow)
          va += lshare[ow][t * 256 + r * 64 + lane];
        va += __shfl_xor(va, 1);
        va += __shfl_xor(va, 2);
        va += __shfl_xor(va, 4);
        va += __shfl_xor(va, 8);
        ls[t][r] = va;
      }
#pragma unroll
      for (int ht = 0; ht < 4; ++ht)
#pragma unroll
        for (int r = 0; r < 4; ++r)
          out[((size_t)b * T_SEQ + r0t[t] + quad * 4 + r) * H_DIM + ht * 16 +
              n16] = O[t][ht][r] / ls[t][r];
    }
  }
}

extern "C" void kernel_launch(void* const* d_in, const int* in_sizes, int n_in,
                              void* d_out, int out_size, void* d_ws,
                              size_t ws_size, hipStream_t stream) {
  const float* x = (const float*)d_in[0];
  const float* Wq = (const float*)d_in[1];
  const float* Wk = (const float*)d_in[2];
  const float* Wv = (const float*)d_in[3];

  char* ws = (char*)d_ws;
  short* Wt = (short*)ws;                       // 384 KB (fragment-linear)
  short* q = (short*)(ws + 3 * 64 * 1024 * 2);  // 2 MB each
  short* kk = (short*)(ws + 3 * 64 * 1024 * 2 + 2097152);
  short* vt = (short*)(ws + 3 * 64 * 1024 * 2 + 2 * 2097152);

  w_prep<<<96, 256, 0, stream>>>(Wq, Wk, Wv, Wt);
  qkv_gemm<<<NROW / 32, 256, 0, stream>>>(x, Wt, q, kk, vt);
  attn_mfma<<<B_DIM * (T_SEQ / 64), 256, 0, stream>>>(q, kk, vt, (float*)d_out);
}

// Round 10
// 133.109 us; speedup vs baseline: 1.0889x; 1.0052x over previous
//
#include <hip/hip_runtime.h>

#define T_SEQ 2048
#define C_DIM 1024
#define H_DIM 64
#define B_DIM 8
#define NROW (B_DIM * T_SEQ)  // 16384

typedef __attribute__((ext_vector_type(8))) short short8;
typedef __attribute__((ext_vector_type(4))) float f32x4;
typedef __attribute__((ext_vector_type(4))) int i32x4;

__device__ __forceinline__ short f2bf(float f) {
  unsigned u = __builtin_bit_cast(unsigned, f);
  u += 0x7fffu + ((u >> 16) & 1u);  // round-to-nearest-even
  return (short)(u >> 16);
}

// pack two f32 -> one u32 of 2 bf16 (RNE, same bits as f2bf pair)
__device__ __forceinline__ unsigned pk_bf16(float lo, float hi) {
  unsigned r;
  asm("v_cvt_pk_bf16_f32 %0, %1, %2" : "=v"(r) : "v"(lo), "v"(hi));
  return r;
}

// ---------------------------------------------------------------------------
// P: Wt2 in FRAGMENT-LINEAR order (unchanged).
// ---------------------------------------------------------------------------
__global__ __launch_bounds__(256) void w_prep(
    const float* __restrict__ Wq, const float* __restrict__ Wk,
    const float* __restrict__ Wv, short* __restrict__ Wt2) {
  const int unit = blockIdx.x * 256 + threadIdx.x;  // 0..24575
  const int lane = unit & 63;
  const int t = unit >> 6;
  const int kh = t & 3;
  const int g = t >> 2;    // kc*12 + ntg
  const int ntg = g % 12;
  const int kc = g / 12;
  const int n16 = lane & 15, quad = lane >> 4;
  const int mat = ntg >> 2;
  const int h = (ntg & 3) * 16 + n16;
  const int kb = kc * 128 + kh * 32 + quad * 8;
  const float* W = (mat == 0) ? Wq : (mat == 1 ? Wk : Wv);
  short8 v;
#pragma unroll
  for (int e = 0; e < 8; ++e) v[e] = f2bf(W[(size_t)(kb + e) * H_DIM + h]);
  *(short8*)(Wt2 + (size_t)unit * 8) = v;
}

// LDS address (in shorts) for A frag unit (tile, kh, quad, n16); XOR-swizzled.
__device__ __forceinline__ int lds_addr(int tile, int kh, int qd, int nn) {
  return tile * 2048 + kh * 512 + (qd * 16 + (nn ^ ((kh * 4 + qd) & 7))) * 8;
}

// ---------------------------------------------------------------------------
// K1: QKV projection, BM=32, grid 512 -- R2 structure with A-PREFETCH DEPTH
// 2 -> 3.  Diagnosis: 2925 cy/chunk vs ~400 cy of issue+MFMA; waves stall in
// s_waitcnt on A.  NOT raw BW: Little's law at 6.3 TB/s needs ~22.5 KB in
// flight per CU; 2-deep holds exactly one chunk's worth (~32 KB marginal,
// barrier lockstep degrades it) -> measured 3.3 TB/s.  3-deep astg[3][4]
// holds 2-3 chunks (~64-96 KB/CU) with ZERO extra traffic, +16 VGPR (~160,
// no spill under the (256,2) cap).  Same barriers, same accumulation order
// -> bit-identical output.
// ---------------------------------------------------------------------------
__global__ __launch_bounds__(256, 2) void qkv_gemm(
    const float* __restrict__ x, const short* __restrict__ Wt2,
    short* __restrict__ q, short* __restrict__ k, short* __restrict__ vt) {
  __shared__ __align__(16) short As[2][4096];  // 2 x 8 KB (32 x 128 bf16)
  const int tid = threadIdx.x;
  const int w = tid >> 6, lane = tid & 63;
  const int n16 = lane & 15, quad = lane >> 4;
  const int row0 = blockIdx.x * 32;

  f32x4 acc[2][3];
#pragma unroll
  for (int mt = 0; mt < 2; ++mt)
#pragma unroll
    for (int ln = 0; ln < 3; ++ln) acc[mt][ln] = (f32x4){0.f, 0.f, 0.f, 0.f};

  const int u20 = tid, u21 = 256 + tid;
  const int sr0 = u20 >> 4, f0 = u20 & 15;
  const int sr1 = u21 >> 4, f1 = u21 & 15;
  const float* ap0 = x + (size_t)(row0 + sr0) * C_DIM + f0 * 8;
  const float* ap1 = x + (size_t)(row0 + sr1) * C_DIM + f1 * 8;
  const int soff0 = lds_addr(sr0 >> 4, f0 >> 2, f0 & 3, sr0 & 15);
  const int soff1 = lds_addr(sr1 >> 4, f1 >> 2, f1 & 3, sr1 & 15);

  int swz[4];
#pragma unroll
  for (int kh = 0; kh < 4; ++kh)
    swz[kh] = (quad * 16 + (n16 ^ ((kh * 4 + quad) & 7))) * 8;

  const short* bbase = Wt2 + (size_t)(w * 3) * 2048 + (size_t)lane * 8;

  float4 astg[3][4];  // 3-deep A ring buffer (chunk kc lives in astg[kc%3])
  short8 bfr[12];

#define LOAD_A(d, kcc)                                     \
  {                                                        \
    astg[d][0] = *(const float4*)(ap0 + (kcc) * 128);      \
    astg[d][1] = *(const float4*)(ap0 + (kcc) * 128 + 4);  \
    astg[d][2] = *(const float4*)(ap1 + (kcc) * 128);      \
    astg[d][3] = *(const float4*)(ap1 + (kcc) * 128 + 4);  \
  }

#define STAGE_A(d, p)                                      \
  {                                                        \
    short8 av0, av1;                                       \
    _Pragma("unroll") for (int e = 0; e < 4; ++e) {        \
      av0[e] = f2bf(((const float*)&astg[d][0])[e]);       \
      av0[e + 4] = f2bf(((const float*)&astg[d][1])[e]);   \
      av1[e] = f2bf(((const float*)&astg[d][2])[e]);       \
      av1[e + 4] = f2bf(((const float*)&astg[d][3])[e]);   \
    }                                                      \
    *(short8*)(&As[p][0] + soff0) = av0;                   \
    *(short8*)(&As[p][0] + soff1) = av1;                   \
  }

  // prologue: issue A(0..2) and B(0); stage A(0)
  LOAD_A(0, 0);
  LOAD_A(1, 1);
  LOAD_A(2, 2);
#pragma unroll
  for (int ln = 0; ln < 3; ++ln)
#pragma unroll
    for (int kh = 0; kh < 4; ++kh)
      bfr[ln * 4 + kh] = *(const short8*)(bbase + ln * 2048 + kh * 512);
  STAGE_A(0, 0);  // waits only A(0)'s 4 loads (oldest)
  asm volatile("s_waitcnt lgkmcnt(0)" ::: "memory");
  __builtin_amdgcn_sched_barrier(0);
  __builtin_amdgcn_s_barrier();
  __builtin_amdgcn_sched_barrier(0);

#pragma unroll
  for (int kc = 0; kc < 8; ++kc) {
    const short* asb = &As[kc & 1][0];
#pragma unroll
    for (int kh = 0; kh < 4; ++kh) {
      const short8 a0 = *(const short8*)(asb + kh * 512 + swz[kh]);
      const short8 a1 = *(const short8*)(asb + 2048 + kh * 512 + swz[kh]);
#pragma unroll
      for (int ln = 0; ln < 3; ++ln) {
        acc[0][ln] = __builtin_amdgcn_mfma_f32_16x16x32_bf16(
            a0, bfr[ln * 4 + kh], acc[0][ln], 0, 0, 0);
        acc[1][ln] = __builtin_amdgcn_mfma_f32_16x16x32_bf16(
            a1, bfr[ln * 4 + kh], acc[1][ln], 0, 0, 0);
      }
    }
    if (kc < 7) {
      const short* bc = bbase + (size_t)(kc + 1) * 24576;
#pragma unroll
      for (int ln = 0; ln < 3; ++ln)
#pragma unroll
        for (int kh = 0; kh < 4; ++kh)
          bfr[ln * 4 + kh] = *(const short8*)(bc + ln * 2048 + kh * 512);
      if (kc < 5) {
        // issue A(kc+3) into the slot whose chunk (kc) was staged last iter
        LOAD_A(kc % 3, kc + 3);
      }
      // stage A(kc+1) (loaded 3 iters ago -- latency long since covered)
      STAGE_A((kc + 1) % 3, (kc + 1) & 1);
      asm volatile("s_waitcnt lgkmcnt(0)" ::: "memory");
      __builtin_amdgcn_sched_barrier(0);
      __builtin_amdgcn_s_barrier();
      __builtin_amdgcn_sched_barrier(0);
    }
  }
#undef STAGE_A
#undef LOAD_A

  const int b = row0 >> 11;
#pragma unroll
  for (int mt = 0; mt < 2; ++mt)
#pragma unroll
    for (int ln = 0; ln < 3; ++ln) {
      const int ntg = w * 3 + ln;
      const int mat = ntg >> 2;
      const int cl = (ntg & 3) * 16 + n16;
#pragma unroll
      for (int r = 0; r < 4; ++r) {
        const int row = row0 + mt * 16 + quad * 4 + r;
        const float v = acc[mt][ln][r];
        if (mat == 0)
          q[(size_t)row * H_DIM + cl] = f2bf(v * 0.125f);
        else if (mat == 1)
          k[(size_t)row * H_DIM + cl] = f2bf(v);
        else
          vt[((size_t)b * H_DIM + cl) * T_SEQ + (row & (T_SEQ - 1))] = f2bf(v);
      }
    }
}

// ---------------------------------------------------------------------------
// K2: QUARTET-tile flash attention + in-register softmax -- exact R9 kernel
// (best measured: 133.8 total).
// ---------------------------------------------------------------------------
__global__ __launch_bounds__(256) void attn_mfma(
    const short* __restrict__ q, const short* __restrict__ k,
    const short* __restrict__ vt, float* __restrict__ out) {
  __shared__ __align__(16) float oshare[3][4096];  // 4 tiles x 1024
  __shared__ __align__(16) float lshare[3][1024];  // 4 tiles x 256
  const int tid = threadIdx.x;
  const int w = tid >> 6;
  const int lane = tid & 63;
  const int n16 = lane & 15, quad = lane >> 4;
  const int b = blockIdx.x & 7;   // b == XCD slot -> K/V L2-resident
  const int g = blockIdx.x >> 3;  // 0..31

  int r0t[4], nj[4];
  r0t[0] = g * 16;
  r0t[1] = (63 - g) * 16;
  r0t[2] = (64 + g) * 16;
  r0t[3] = (127 - g) * 16;
#pragma unroll
  for (int t = 0; t < 4; ++t) nj[t] = (r0t[t] + 79) >> 6;

  const short* kb = k + (size_t)b * T_SEQ * H_DIM;
  const short* vb = vt + (size_t)b * H_DIM * T_SEQ;

  short8 aq[4][2];
#pragma unroll
  for (int t = 0; t < 4; ++t) {
    const short* qp = q + ((size_t)b * T_SEQ + r0t[t] + n16) * H_DIM;
    aq[t][0] = *(const short8*)(qp + quad * 8);
    aq[t][1] = *(const short8*)(qp + 32 + quad * 8);
  }

  f32x4 O[4][4];
#pragma unroll
  for (int t = 0; t < 4; ++t)
#pragma unroll
    for (int i = 0; i < 4; ++i) O[t][i] = (f32x4){0.f, 0.f, 0.f, 0.f};
  float lssc[4] = {0.f, 0.f, 0.f, 0.f};  // per-lane partial for row = n16

  for (int jt = w; jt < nj[3]; jt += 4) {
    const int j0 = jt * 64;

    short8 bk[4][2];
#pragma unroll
    for (int nt = 0; nt < 4; ++nt) {
      const short* kp = kb + (size_t)(j0 + nt * 16 + n16) * H_DIM + quad * 8;
      bk[nt][0] = *(const short8*)kp;
      bk[nt][1] = *(const short8*)(kp + 32);
    }

    // --- per tile: swapped QK, exp+mask, register pack ---
    unsigned wp[4][4][2];
#pragma unroll
    for (int t = 0; t < 4; ++t) {
      if (jt < nj[t]) {  // wave-uniform
        f32x4 s[4];
#pragma unroll
        for (int nt = 0; nt < 4; ++nt) {
          f32x4 z = (f32x4){0.f, 0.f, 0.f, 0.f};
          z = __builtin_amdgcn_mfma_f32_16x16x32_bf16(bk[nt][0], aq[t][0], z, 0, 0, 0);
          z = __builtin_amdgcn_mfma_f32_16x16x32_bf16(bk[nt][1], aq[t][1], z, 0, 0, 0);
          s[nt] = z;
        }
        const bool full = (j0 + 64 <= r0t[t]);
#pragma unroll
        for (int nt = 0; nt < 4; ++nt) {
          float p[4];
#pragma unroll
          for (int r = 0; r < 4; ++r) {
            if (full) {
              p[r] = __expf(s[nt][r]);
            } else {
              const int j = j0 + nt * 16 + quad * 4 + r;
              p[r] = (j <= r0t[t] + n16) ? __expf(s[nt][r]) : 0.f;
            }
            lssc[t] += p[r];
          }
          wp[t][nt][0] = pk_bf16(p[0], p[1]);
          wp[t][nt][1] = pk_bf16(p[2], p[3]);
        }
      }
    }

    // --- V fragments (shared by all active tiles) ---
    short8 bv[4][2];
#pragma unroll
    for (int ht = 0; ht < 4; ++ht)
#pragma unroll
      for (int kh = 0; kh < 2; ++kh)
        bv[ht][kh] = *(const short8*)(vb + (size_t)(ht * 16 + n16) * T_SEQ +
                                      j0 + kh * 32 + quad * 8);

    // --- in-register exchange -> PV A-fragments, then PV (per tile) ---
#define EXCHANGE(WSRC, AP0, AP1)                                          \
  {                                                                       \
    i32x4 apw[2];                                                         \
    _Pragma("unroll") for (int h = 0; h < 2; ++h) {                       \
      _Pragma("unroll") for (int ww = 0; ww < 2; ++ww) {                  \
        const unsigned wlo = WSRC[2 * h][ww];                             \
        const unsigned whi = WSRC[2 * h + 1][ww];                         \
        const unsigned pay16 = (quad >= 2) ? whi : wlo;                   \
        const unsigned pay2 = (quad < 2) ? whi : wlo;                     \
        const unsigned x16 = (unsigned)__shfl_xor((int)pay16, 16);        \
        const unsigned x32 = (unsigned)__shfl_xor((int)pay2, 32);         \
        const unsigned x48 = (unsigned)__shfl_xor((int)pay2, 48);         \
        const unsigned lo =                                               \
            quad == 0 ? wlo : quad == 1 ? x48 : quad == 2 ? x32 : x16;    \
        const unsigned hi =                                               \
            quad == 0 ? x16 : quad == 1 ? x32 : quad == 2 ? x48 : whi;    \
        apw[h][ww] = (int)lo;                                             \
        apw[h][2 + ww] = (int)hi;                                         \
      }                                                                   \
    }                                                                     \
    AP0 = __builtin_bit_cast(short8, apw[0]);                             \
    AP1 = __builtin_bit_cast(short8, apw[1]);                             \
  }

#pragma unroll
    for (int t = 0; t < 4; ++t) {
      if (jt < nj[t]) {  // wave-uniform
        short8 ap0, ap1;
        EXCHANGE(wp[t], ap0, ap1);
#pragma unroll
        for (int ht = 0; ht < 4; ++ht) {
          O[t][ht] = __builtin_amdgcn_mfma_f32_16x16x32_bf16(ap0, bv[ht][0], O[t][ht], 0, 0, 0);
          O[t][ht] = __builtin_amdgcn_mfma_f32_16x16x32_bf16(ap1, bv[ht][1], O[t][ht], 0, 0, 0);
        }
      }
    }
#undef EXCHANGE
  }

  // remap scalar row-partials (row = n16) to the (quad,r) convention:
  // row (quad*4+r)'s four quad-partials land at n16 = 0..3; zeros elsewhere.
  // The unchanged epilogue's xor(1,2,4,8) reduction then sums them exactly.
  float ls[4][4];
#pragma unroll
  for (int t = 0; t < 4; ++t)
#pragma unroll
    for (int r = 0; r < 4; ++r) {
      const int src = (n16 & 3) * 16 + quad * 4 + r;
      const float v = __shfl(lssc[t], src);
      ls[t][r] = (n16 < 4) ? v : 0.f;
    }

  // --- cross-wave reduction (R2 pattern, 4 tiles) ---
  if (w != 0) {
#pragma unroll
    for (int t = 0; t < 4; ++t) {
#pragma unroll
      for (int ht = 0; ht < 4; ++ht)
#pragma unroll
        for (int r = 0; r < 4; ++r)
          oshare[w - 1][t * 1024 + (ht * 4 + r) * 64 + lane] = O[t][ht][r];
#pragma unroll
      for (int r = 0; r < 4; ++r)
        lshare[w - 1][t * 256 + r * 64 + lane] = ls[t][r];
    }
  }
  __syncthreads();
  if (w == 0) {
#pragma unroll
    for (int t = 0; t < 4; ++t) {
#pragma unroll
      for (int ht = 0; ht < 4; ++ht)
#pragma unroll
        for (int r = 0; r < 4; ++r) {
          float a = O[t][ht][r];
#pragma unroll
          for (int ow = 0; ow < 3; ++ow)
            a += oshare[ow][t * 1024 + (ht * 4 + r) * 64 + lane];
          O[t][ht][r] = a;
        }
#pragma unroll
      for (int r = 0; r < 4; ++r) {
        float va = ls[t][r];
#pragma unroll
        for (int ow = 0; ow < 3; ++ow)
          va += lshare[ow][t * 256 + r * 64 + lane];
        va += __shfl_xor(va, 1);
        va += __shfl_xor(va, 2);
        va += __shfl_xor(va, 4);
        va += __shfl_xor(va, 8);
        ls[t][r] = va;
      }
#pragma unroll
      for (int ht = 0; ht < 4; ++ht)
#pragma unroll
        for (int r = 0; r < 4; ++r)
          out[((size_t)b * T_SEQ + r0t[t] + quad * 4 + r) * H_DIM + ht * 16 +
              n16] = O[t][ht][r] / ls[t][r];
    }
  }
}

extern "C" void kernel_launch(void* const* d_in, const int* in_sizes, int n_in,
                              void* d_out, int out_size, void* d_ws,
                              size_t ws_size, hipStream_t stream) {
  const float* x = (const float*)d_in[0];
  const float* Wq = (const float*)d_in[1];
  const float* Wk = (const float*)d_in[2];
  const float* Wv = (const float*)d_in[3];

  char* ws = (char*)d_ws;
  short* Wt = (short*)ws;                       // 384 KB (fragment-linear)
  short* q = (short*)(ws + 3 * 64 * 1024 * 2);  // 2 MB each
  short* kk = (short*)(ws + 3 * 64 * 1024 * 2 + 2097152);
  short* vt = (short*)(ws + 3 * 64 * 1024 * 2 + 2 * 2097152);

  w_prep<<<96, 256, 0, stream>>>(Wq, Wk, Wv, Wt);
  qkv_gemm<<<NROW / 32, 256, 0, stream>>>(x, Wt, q, kk, vt);
  attn_mfma<<<B_DIM * (T_SEQ / 64), 256, 0, stream>>>(q, kk, vt, (float*)d_out);
}